// Round 3
// baseline (752.904 us; speedup 1.0000x reference)
//
#include <hip/hip_runtime.h>

#define BROWS 16384
#define NCOL  1000
#define NPAD  1024
#define MATSZ ((size_t)NPAD * NPAD)

typedef __attribute__((ext_vector_type(8))) short short8;
typedef __attribute__((ext_vector_type(4))) float f32x4;

__device__ inline unsigned short bf16_rn(float f) {
    unsigned int u = __float_as_uint(f);
    unsigned int r = (u + 0x7fffu + ((u >> 16) & 1u)) >> 16;
    return (unsigned short)r;
}

// ---------------- kernel-matrix generation ----------------
// Layout: for a in {0,1,2}: C_a [1024x1024] bf16, S_a [1024x1024] bf16.
// a==1 is the plain DFT (alpha=1, no 1/N); a==0 -> alpha=0.5, a==2 -> alpha=1.5 (with 1/N).
__global__ __launch_bounds__(256) void gen_kmats(unsigned short* __restrict__ K)
{
    unsigned int idx = blockIdx.x * 256u + threadIdx.x;   // over 3*2^20
    unsigned int a   = idx >> 20;
    unsigned int rem = idx & (unsigned int)(MATSZ - 1);
    int k = (int)(rem >> 10);
    int m = (int)(rem & 1023u);
    float c = 0.f, s = 0.f;
    if (k < NCOL && m < NCOL) {
        if (a == 1) {
            unsigned int p = (unsigned int)(k * m) % 1000u;
            float ang = 6.28318530717958647692f * 0.001f * (float)p;
            float sv, cv; sincosf(ang, &sv, &cv);
            c = cv; s = -sv;
        } else {
            // theta = (pi*alpha/1e6) * (0.5*(m^2+k^2) - 2*k*m); exact half-integer argument
            float coef = (a == 0) ? (float)(3.14159265358979323846 * 0.5e-6)
                                  : (float)(3.14159265358979323846 * 1.5e-6);
            float V = 0.5f * (float)(m * m + k * k) - 2.0f * (float)(k * m);
            float theta = coef * V;
            float sv, cv; sincosf(theta, &sv, &cv);
            c = cv * 0.001f; s = sv * 0.001f;
        }
    }
    unsigned short* Cm = K + (size_t)a * 2 * MATSZ;
    unsigned short* Sm = Cm + MATSZ;
    Cm[rem] = bf16_rn(c);
    Sm[rem] = bf16_rn(s);
}

// ---------------- x (fp32) -> Apad (bf16, zero-padded to 1024 cols) ----------------
__global__ __launch_bounds__(256) void conv_kernel(const float* __restrict__ x,
                                                   unsigned short* __restrict__ Apad)
{
    unsigned int idx = blockIdx.x * 256u + threadIdx.x;   // over 16384*128 groups of 8
    unsigned int row = idx >> 7;
    unsigned int cg  = (idx & 127u) << 3;                 // 0,8,...,1016
    short8 pk = {};
    if (cg < NCOL) {                                      // 1000 % 8 == 0: group fully in-range
        const float* p = x + (size_t)row * NCOL + cg;
        float4 f0 = *(const float4*)p;
        float4 f1 = *(const float4*)(p + 4);
        pk[0] = (short)bf16_rn(f0.x); pk[1] = (short)bf16_rn(f0.y);
        pk[2] = (short)bf16_rn(f0.z); pk[3] = (short)bf16_rn(f0.w);
        pk[4] = (short)bf16_rn(f1.x); pk[5] = (short)bf16_rn(f1.y);
        pk[6] = (short)bf16_rn(f1.z); pk[7] = (short)bf16_rn(f1.w);
    }
    *reinterpret_cast<short8*>(Apad + (size_t)row * NPAD + cg) = pk;
}

// ---------------- plain cross-entropy on fp32 logits ----------------
__global__ __launch_bounds__(256) void ce_kernel(const float* __restrict__ logits,
                                                 const int* __restrict__ tgt,
                                                 float* __restrict__ acc)
{
    int row = blockIdx.x;
    const float* p = logits + (size_t)row * NCOL;
    int t = threadIdx.x;
    float lmax = -INFINITY;
    for (int c = t; c < NCOL; c += 256) lmax = fmaxf(lmax, p[c]);
    #pragma unroll
    for (int off = 1; off < 64; off <<= 1) lmax = fmaxf(lmax, __shfl_xor(lmax, off));
    __shared__ float sm[4], ss[4];
    int w = t >> 6;
    if ((t & 63) == 0) sm[w] = lmax;
    __syncthreads();
    float bmax = fmaxf(fmaxf(sm[0], sm[1]), fmaxf(sm[2], sm[3]));
    float lsum = 0.f;
    for (int c = t; c < NCOL; c += 256) lsum += expf(p[c] - bmax);
    #pragma unroll
    for (int off = 1; off < 64; off <<= 1) lsum += __shfl_xor(lsum, off);
    if ((t & 63) == 0) ss[w] = lsum;
    __syncthreads();
    if (t == 0) {
        float bsum = ss[0] + ss[1] + ss[2] + ss[3];
        float nll = bmax + logf(bsum) - p[tgt[row]];
        atomicAdd(acc, nll);
    }
}

// ---------------- fused FrFT GEMM + online-softmax CE ----------------
// grid: (BROWS/64, 3). Block: 256 thr = 4 waves. Per k-chunk of 64 output cols,
// each wave computes a 16(row)x64(col) tile: accre/accim via mfma 16x16x32 bf16,
// contraction over m in 32-wide chunks (padded to 1024).
// BF16A: A pre-converted to bf16 in Apad (ws); else convert fp32 x inline.
template<bool BF16A>
__global__ __launch_bounds__(256) void frft_kernel(const float* __restrict__ x,
                                                   const unsigned short* __restrict__ Apad,
                                                   const int* __restrict__ tgt,
                                                   const unsigned short* __restrict__ K,
                                                   float* __restrict__ acc)
{
    const int aid   = blockIdx.y;
    const int rbase = blockIdx.x * 64;
    const unsigned short* Cm = K + (size_t)aid * 2 * MATSZ;
    const unsigned short* Sm = Cm + MATSZ;

    __shared__ unsigned short lA[64 * 40];
    __shared__ unsigned short lC[64 * 40];
    __shared__ unsigned short lS[64 * 40];

    const int tid = threadIdx.x;
    const int w   = tid >> 6;
    const int l   = tid & 63;
    const int l15 = l & 15;
    const int lhi = l >> 4;

    const int srow = tid >> 2;          // 0..63
    const int scol = (tid & 3) << 3;    // 0,8,16,24

    // CE state: lane holds rows w*16 + lhi*4 + j (matches MFMA D layout)
    float m_run[4], s_run[4], tval[4];
    int   tg[4];
    #pragma unroll
    for (int j = 0; j < 4; ++j) {
        m_run[j] = -INFINITY; s_run[j] = 0.f; tval[j] = 0.f;
        tg[j] = tgt[rbase + w * 16 + lhi * 4 + j];
    }

    const float*          xA = x    + (size_t)(rbase + srow) * NCOL;
    const unsigned short* bA = Apad + (size_t)(rbase + srow) * NPAD;

    for (int kc = 0; kc < 16; ++kc) {
        f32x4 accre[4] = {}, accim[4] = {};
        const int kb = kc << 6;
        for (int mc = 0; mc < 32; ++mc) {
            const int mb = mc << 5;
            // stage A
            if constexpr (BF16A) {
                *reinterpret_cast<short8*>(&lA[srow * 40 + scol]) =
                    *reinterpret_cast<const short8*>(bA + mb + scol);
            } else {
                int gm = mb + scol;
                short8 pk = {};
                if (gm < NCOL) {
                    float4 f0 = *(const float4*)(xA + gm);
                    float4 f1 = *(const float4*)(xA + gm + 4);
                    pk[0] = (short)bf16_rn(f0.x); pk[1] = (short)bf16_rn(f0.y);
                    pk[2] = (short)bf16_rn(f0.z); pk[3] = (short)bf16_rn(f0.w);
                    pk[4] = (short)bf16_rn(f1.x); pk[5] = (short)bf16_rn(f1.y);
                    pk[6] = (short)bf16_rn(f1.z); pk[7] = (short)bf16_rn(f1.w);
                }
                *reinterpret_cast<short8*>(&lA[srow * 40 + scol]) = pk;
            }
            // stage C, S (raw bf16 16B copies; matrices are zero-padded)
            {
                const size_t gro = (size_t)(kb + srow) * NPAD + mb + scol;
                *reinterpret_cast<short8*>(&lC[srow * 40 + scol]) =
                    *reinterpret_cast<const short8*>(Cm + gro);
                *reinterpret_cast<short8*>(&lS[srow * 40 + scol]) =
                    *reinterpret_cast<const short8*>(Sm + gro);
            }
            __syncthreads();
            short8 af = *reinterpret_cast<const short8*>(&lA[(w * 16 + l15) * 40 + lhi * 8]);
            #pragma unroll
            for (int cf = 0; cf < 4; ++cf) {
                short8 bc = *reinterpret_cast<const short8*>(&lC[(cf * 16 + l15) * 40 + lhi * 8]);
                short8 bs = *reinterpret_cast<const short8*>(&lS[(cf * 16 + l15) * 40 + lhi * 8]);
                accre[cf] = __builtin_amdgcn_mfma_f32_16x16x32_bf16(af, bc, accre[cf], 0, 0, 0);
                accim[cf] = __builtin_amdgcn_mfma_f32_16x16x32_bf16(af, bs, accim[cf], 0, 0, 0);
            }
            __syncthreads();
        }
        // online CE update over this 64-col chunk
        float v[4][4];
        #pragma unroll
        for (int cf = 0; cf < 4; ++cf) {
            int col = kb + cf * 16 + l15;
            bool cv = (col < NCOL);
            #pragma unroll
            for (int j = 0; j < 4; ++j) {
                float re = accre[cf][j], im = accim[cf][j];
                float mag = sqrtf(re * re + im * im);
                if (cv && col == tg[j]) tval[j] = mag;
                v[cf][j] = cv ? mag : -INFINITY;
            }
        }
        #pragma unroll
        for (int j = 0; j < 4; ++j) {
            float cmax = fmaxf(fmaxf(v[0][j], v[1][j]), fmaxf(v[2][j], v[3][j]));
            #pragma unroll
            for (int off = 1; off < 16; off <<= 1) cmax = fmaxf(cmax, __shfl_xor(cmax, off));
            float mn = fmaxf(m_run[j], cmax);
            float ps = 0.f;
            #pragma unroll
            for (int cf = 0; cf < 4; ++cf) ps += expf(v[cf][j] - mn);
            #pragma unroll
            for (int off = 1; off < 16; off <<= 1) ps += __shfl_xor(ps, off);
            s_run[j] = s_run[j] * expf(m_run[j] - mn) + ps;
            m_run[j] = mn;
        }
    }
    // finalize rows; tval: exactly one lane in each 16-lane group holds the target value
    float nll_part = 0.f;
    #pragma unroll
    for (int j = 0; j < 4; ++j) {
        float tv = tval[j];
        #pragma unroll
        for (int off = 1; off < 16; off <<= 1) tv += __shfl_xor(tv, off);
        if (l15 == 0) nll_part += m_run[j] + logf(s_run[j]) - tv;
    }
    nll_part += __shfl_xor(nll_part, 16);
    nll_part += __shfl_xor(nll_part, 32);
    __shared__ float wpart[4];
    if (l == 0) wpart[w] = nll_part;
    __syncthreads();
    if (tid == 0) atomicAdd(acc + 1, wpart[0] + wpart[1] + wpart[2] + wpart[3]);
}

__global__ void final_kernel(const float* __restrict__ acc, float* __restrict__ out)
{
    if (threadIdx.x == 0)
        out[0] = acc[0] * (1.0f / (float)BROWS)
               + 0.5f * acc[1] * (1.0f / (3.0f * (float)BROWS));
}

extern "C" void kernel_launch(void* const* d_in, const int* in_sizes, int n_in,
                              void* d_out, int out_size, void* d_ws, size_t ws_size,
                              hipStream_t stream)
{
    const float* logits  = (const float*)d_in[0];
    const int*   targets = (const int*)d_in[1];
    float* out = (float*)d_out;

    float* acc = (float*)d_ws;                                   // acc[0]=ce_sum, acc[1]=frft_sum
    unsigned short* K = (unsigned short*)((char*)d_ws + 256);    // 6 x 2MB bf16 matrices
    unsigned short* Apad = K + 6 * MATSZ;                        // 32MB bf16 [16384x1024]
    const size_t need_bf16a = 256 + 6 * MATSZ * 2 + (size_t)BROWS * NPAD * 2;
    const bool use_bf16a = (ws_size >= need_bf16a);

    hipMemsetAsync(acc, 0, 2 * sizeof(float), stream);
    gen_kmats<<<(3 * (1u << 20)) / 256, 256, 0, stream>>>(K);
    ce_kernel<<<BROWS, 256, 0, stream>>>(logits, targets, acc);
    dim3 g(BROWS / 64, 3);
    if (use_bf16a) {
        conv_kernel<<<(BROWS * (NPAD / 8)) / 256, 256, 0, stream>>>(logits, Apad);
        frft_kernel<true><<<g, 256, 0, stream>>>(logits, Apad, targets, K, acc);
    } else {
        frft_kernel<false><<<g, 256, 0, stream>>>(logits, Apad, targets, K, acc);
    }
    final_kernel<<<1, 64, 0, stream>>>(acc, out);
}

// Round 5
// 731.054 us; speedup vs baseline: 1.0299x; 1.0299x over previous
//
#include <hip/hip_runtime.h>

#define BROWS 16384
#define NCOL  1000
#define NPAD  1024
#define NPRIME 2048                      // interleaved re/im cols
#define BAELEM ((size_t)NPRIME * NPAD)   // 2,097,152 ushorts per alpha

typedef __attribute__((ext_vector_type(8))) short short8;
typedef __attribute__((ext_vector_type(4))) float f32x4;

__device__ inline unsigned short bf16_rn(float f) {
    unsigned int u = __float_as_uint(f);
    unsigned int r = (u + 0x7fffu + ((u >> 16) & 1u)) >> 16;
    return (unsigned short)r;
}
// LDS bank swizzle: 16B slot ^= (row>>1)&3  (row = byte>>6). 2-way max conflict.
__device__ inline int swzb(int b) { return b ^ (((b >> 7) & 3) << 4); }

__device__ inline void gload16(const void* g, void* l) {
    __builtin_amdgcn_global_load_lds(
        (const __attribute__((address_space(1))) unsigned int*)g,
        (__attribute__((address_space(3))) unsigned int*)l, 16, 0, 0);
}

__device__ inline short8 pack8(float4 a, float4 b) {
    short8 r;
    r[0] = (short)bf16_rn(a.x); r[1] = (short)bf16_rn(a.y);
    r[2] = (short)bf16_rn(a.z); r[3] = (short)bf16_rn(a.w);
    r[4] = (short)bf16_rn(b.x); r[5] = (short)bf16_rn(b.y);
    r[6] = (short)bf16_rn(b.z); r[7] = (short)bf16_rn(b.w);
    return r;
}

// ---------------- B' generation: interleaved, k-tiled, pre-swizzled ----------------
// Global layout per alpha: 32 k-tiles x [2048 cols x 32 k] with swzb() applied to the
// byte-within-tile, so a linear global_load_lds lands the swizzle in LDS (rule 21).
__global__ __launch_bounds__(256) void gen_b(unsigned short* __restrict__ Bg)
{
    unsigned int idx = blockIdx.x * 256u + threadIdx.x;   // 3 * 2^20 pairs
    int a = idx >> 20;
    unsigned int rem = idx & 0xFFFFFu;
    int q = rem >> 10, m = rem & 1023;
    float cv = 0.f, sv = 0.f;
    if (q < NCOL && m < NCOL) {
        if (a == 1) {
            int p = (q * m) % 1000;
            float ang = 6.28318530717958f * 0.001f * (float)p;
            __sincosf(ang, &sv, &cv);
            sv = -sv;
        } else {
            float coef = (a == 0) ? 3.14159265358979f * 0.5e-6f
                                  : 3.14159265358979f * 1.5e-6f;
            float V = 0.5f * (float)(m * m + q * q) - 2.0f * (float)(q * m);
            float th = coef * V;
            __sincosf(th, &sv, &cv);
            cv *= 0.001f; sv *= 0.001f;
        }
    }
    int kt = m >> 5, lk = m & 31;
    size_t base = (size_t)a * BAELEM + (size_t)kt * 65536;  // ushort units
    int b0 = swzb((2 * q) * 64 + lk * 2);
    int b1 = swzb((2 * q + 1) * 64 + lk * 2);
    Bg[base + (b0 >> 1)] = bf16_rn(cv);
    Bg[base + (b1 >> 1)] = bf16_rn(sv);
}

// ---------------- plain cross-entropy on fp32 logits ----------------
__global__ __launch_bounds__(256) void ce_kernel(const float* __restrict__ logits,
                                                 const int* __restrict__ tgt,
                                                 float* __restrict__ acc)
{
    int row = blockIdx.x;
    const float* p = logits + (size_t)row * NCOL;
    int t = threadIdx.x;
    float lmax = -INFINITY;
    for (int c = t; c < NCOL; c += 256) lmax = fmaxf(lmax, p[c]);
    #pragma unroll
    for (int off = 1; off < 64; off <<= 1) lmax = fmaxf(lmax, __shfl_xor(lmax, off));
    __shared__ float sm[4], ss[4];
    int w = t >> 6;
    if ((t & 63) == 0) sm[w] = lmax;
    __syncthreads();
    float bmax = fmaxf(fmaxf(sm[0], sm[1]), fmaxf(sm[2], sm[3]));
    float lsum = 0.f;
    for (int c = t; c < NCOL; c += 256) lsum += expf(p[c] - bmax);
    #pragma unroll
    for (int off = 1; off < 64; off <<= 1) lsum += __shfl_xor(lsum, off);
    if ((t & 63) == 0) ss[w] = lsum;
    __syncthreads();
    if (t == 0) {
        float bsum = ss[0] + ss[1] + ss[2] + ss[3];
        atomicAdd(acc, bmax + logf(bsum) - p[tgt[row]]);
    }
}

// ---------------- 256^2-tile GEMM + partial-logsumexp epilogue ----------------
// grid (512, 3): bx&63 = row-block (256 rows), bx>>6 = col-block (256 of 2048 cols).
// 8 waves (2M x 4N), wave tile 128x64, BK=32, double-buffered LDS (64 KB).
__global__ __launch_bounds__(512, 1) void frft2(const float* __restrict__ x,
                                                const int* __restrict__ tgt,
                                                const unsigned short* __restrict__ Bg,
                                                float2* __restrict__ part,
                                                float* __restrict__ tv)
{
    __shared__ unsigned short lA[2][8192];
    __shared__ unsigned short lB[2][8192];

    const int tid = threadIdx.x;
    const int w = tid >> 6, l = tid & 63, l15 = l & 15, lhi = l >> 4;
    const int wm = w >> 2, wn = w & 3;
    const int aid = blockIdx.y;
    const int rowBase = (blockIdx.x & 63) << 8;
    const int colBase = (blockIdx.x >> 6) << 8;
    const unsigned short* Ba = Bg + (size_t)aid * BAELEM + (size_t)colBase * 32;

    // A staging: 2 passes x (8 fp32 -> short8 -> ds_write_b128)
    const int slot = tid & 3;
    const float* src0 = x + (size_t)(rowBase + (tid >> 2)) * NCOL + slot * 8;
    const float* src1 = x + (size_t)(rowBase + 128 + (tid >> 2)) * NCOL + slot * 8;
    const int d0 = swzb(tid * 16), d1 = swzb(8192 + tid * 16);
    // B staging: 2 global_load_lds (1 KB each) per wave per tile
    const int gu0 = (w * 2 + 0) * 512 + l * 8;   // ushort units (per-lane global)
    const int gu1 = (w * 2 + 1) * 512 + l * 8;
    const int lo0 = (w * 2 + 0) * 1024;          // bytes (wave-uniform LDS base)
    const int lo1 = (w * 2 + 1) * 1024;
    char* lAc = (char*)&lA[0][0];
    char* lBc = (char*)&lB[0][0];

    int ab[8], bb[4];
    #pragma unroll
    for (int mf = 0; mf < 8; ++mf) ab[mf] = swzb((wm * 128 + mf * 16 + l15) * 64 + lhi * 16);
    #pragma unroll
    for (int nf = 0; nf < 4; ++nf) bb[nf] = swzb((wn * 64 + nf * 16 + l15) * 64 + lhi * 16);

    f32x4 acc[8][4] = {};

    // ---- prologue: stage tile 0 into buffer 0 ----
    gload16(Ba + gu0, lBc + lo0);
    gload16(Ba + gu1, lBc + lo1);
    {
        float4 f00 = *(const float4*)(src0), f01 = *(const float4*)(src0 + 4);
        float4 f10 = *(const float4*)(src1), f11 = *(const float4*)(src1 + 4);
        *(short8*)(lAc + d0) = pack8(f00, f01);
        *(short8*)(lAc + d1) = pack8(f10, f11);
    }
    __syncthreads();

    #pragma unroll 2
    for (int kt = 0; kt < 32; ++kt) {
        const int curb = (kt & 1) * 16384;
        const int nxtb = curb ^ 16384;
        const bool pre = (kt < 31);
        const int ktn = kt + 1;

        // prefetch issues for tile kt+1 (B: async to LDS; A: to regs)
        float4 f00 = {0,0,0,0}, f01 = {0,0,0,0}, f10 = {0,0,0,0}, f11 = {0,0,0,0};
        if (pre) {
            const unsigned short* bt = Ba + (size_t)ktn * 65536;
            gload16(bt + gu0, lBc + nxtb + lo0);
            gload16(bt + gu1, lBc + nxtb + lo1);
            if ((ktn < 31) | (slot == 0)) {   // k-range fully valid else zero-pad
                const float* s0 = src0 + ktn * 32;
                const float* s1 = src1 + ktn * 32;
                f00 = *(const float4*)(s0); f01 = *(const float4*)(s0 + 4);
                f10 = *(const float4*)(s1); f11 = *(const float4*)(s1 + 4);
            }
        }

        // P0: read A mf0-3 + B nf0-3, then 16 MFMA
        short8 a0 = *(const short8*)(lAc + curb + ab[0]);
        short8 a1 = *(const short8*)(lAc + curb + ab[1]);
        short8 a2 = *(const short8*)(lAc + curb + ab[2]);
        short8 a3 = *(const short8*)(lAc + curb + ab[3]);
        short8 b0 = *(const short8*)(lBc + curb + bb[0]);
        short8 b1 = *(const short8*)(lBc + curb + bb[1]);
        short8 b2 = *(const short8*)(lBc + curb + bb[2]);
        short8 b3 = *(const short8*)(lBc + curb + bb[3]);
        __builtin_amdgcn_s_barrier();
        __builtin_amdgcn_s_setprio(1);
        acc[0][0] = __builtin_amdgcn_mfma_f32_16x16x32_bf16(a0, b0, acc[0][0], 0, 0, 0);
        acc[0][1] = __builtin_amdgcn_mfma_f32_16x16x32_bf16(a0, b1, acc[0][1], 0, 0, 0);
        acc[0][2] = __builtin_amdgcn_mfma_f32_16x16x32_bf16(a0, b2, acc[0][2], 0, 0, 0);
        acc[0][3] = __builtin_amdgcn_mfma_f32_16x16x32_bf16(a0, b3, acc[0][3], 0, 0, 0);
        acc[1][0] = __builtin_amdgcn_mfma_f32_16x16x32_bf16(a1, b0, acc[1][0], 0, 0, 0);
        acc[1][1] = __builtin_amdgcn_mfma_f32_16x16x32_bf16(a1, b1, acc[1][1], 0, 0, 0);
        acc[1][2] = __builtin_amdgcn_mfma_f32_16x16x32_bf16(a1, b2, acc[1][2], 0, 0, 0);
        acc[1][3] = __builtin_amdgcn_mfma_f32_16x16x32_bf16(a1, b3, acc[1][3], 0, 0, 0);
        acc[2][0] = __builtin_amdgcn_mfma_f32_16x16x32_bf16(a2, b0, acc[2][0], 0, 0, 0);
        acc[2][1] = __builtin_amdgcn_mfma_f32_16x16x32_bf16(a2, b1, acc[2][1], 0, 0, 0);
        acc[2][2] = __builtin_amdgcn_mfma_f32_16x16x32_bf16(a2, b2, acc[2][2], 0, 0, 0);
        acc[2][3] = __builtin_amdgcn_mfma_f32_16x16x32_bf16(a2, b3, acc[2][3], 0, 0, 0);
        acc[3][0] = __builtin_amdgcn_mfma_f32_16x16x32_bf16(a3, b0, acc[3][0], 0, 0, 0);
        acc[3][1] = __builtin_amdgcn_mfma_f32_16x16x32_bf16(a3, b1, acc[3][1], 0, 0, 0);
        acc[3][2] = __builtin_amdgcn_mfma_f32_16x16x32_bf16(a3, b2, acc[3][2], 0, 0, 0);
        acc[3][3] = __builtin_amdgcn_mfma_f32_16x16x32_bf16(a3, b3, acc[3][3], 0, 0, 0);
        __builtin_amdgcn_s_setprio(0);
        __builtin_amdgcn_s_barrier();

        // P1: read A mf4-7, write A stage for kt+1, then 16 MFMA
        a0 = *(const short8*)(lAc + curb + ab[4]);
        a1 = *(const short8*)(lAc + curb + ab[5]);
        a2 = *(const short8*)(lAc + curb + ab[6]);
        a3 = *(const short8*)(lAc + curb + ab[7]);
        if (pre) {
            *(short8*)(lAc + nxtb + d0) = pack8(f00, f01);
            *(short8*)(lAc + nxtb + d1) = pack8(f10, f11);
        }
        __builtin_amdgcn_s_barrier();
        __builtin_amdgcn_s_setprio(1);
        acc[4][0] = __builtin_amdgcn_mfma_f32_16x16x32_bf16(a0, b0, acc[4][0], 0, 0, 0);
        acc[4][1] = __builtin_amdgcn_mfma_f32_16x16x32_bf16(a0, b1, acc[4][1], 0, 0, 0);
        acc[4][2] = __builtin_amdgcn_mfma_f32_16x16x32_bf16(a0, b2, acc[4][2], 0, 0, 0);
        acc[4][3] = __builtin_amdgcn_mfma_f32_16x16x32_bf16(a0, b3, acc[4][3], 0, 0, 0);
        acc[5][0] = __builtin_amdgcn_mfma_f32_16x16x32_bf16(a1, b0, acc[5][0], 0, 0, 0);
        acc[5][1] = __builtin_amdgcn_mfma_f32_16x16x32_bf16(a1, b1, acc[5][1], 0, 0, 0);
        acc[5][2] = __builtin_amdgcn_mfma_f32_16x16x32_bf16(a1, b2, acc[5][2], 0, 0, 0);
        acc[5][3] = __builtin_amdgcn_mfma_f32_16x16x32_bf16(a1, b3, acc[5][3], 0, 0, 0);
        acc[6][0] = __builtin_amdgcn_mfma_f32_16x16x32_bf16(a2, b0, acc[6][0], 0, 0, 0);
        acc[6][1] = __builtin_amdgcn_mfma_f32_16x16x32_bf16(a2, b1, acc[6][1], 0, 0, 0);
        acc[6][2] = __builtin_amdgcn_mfma_f32_16x16x32_bf16(a2, b2, acc[6][2], 0, 0, 0);
        acc[6][3] = __builtin_amdgcn_mfma_f32_16x16x32_bf16(a2, b3, acc[6][3], 0, 0, 0);
        acc[7][0] = __builtin_amdgcn_mfma_f32_16x16x32_bf16(a3, b0, acc[7][0], 0, 0, 0);
        acc[7][1] = __builtin_amdgcn_mfma_f32_16x16x32_bf16(a3, b1, acc[7][1], 0, 0, 0);
        acc[7][2] = __builtin_amdgcn_mfma_f32_16x16x32_bf16(a3, b2, acc[7][2], 0, 0, 0);
        acc[7][3] = __builtin_amdgcn_mfma_f32_16x16x32_bf16(a3, b3, acc[7][3], 0, 0, 0);
        __builtin_amdgcn_s_setprio(0);
        __syncthreads();   // boundary: drains vmcnt (gload_lds) + lgkm (A writes)
    }

    // ---- epilogue: per-row partial logsumexp over this wave's 64 cols ----
    int* tl = (int*)lAc;                      // reuse LDS for targets
    if (tid < 256) tl[tid] = tgt[rowBase + tid];
    __syncthreads();

    const int chunk = (colBase >> 6) + wn;    // global 64-col chunk index (0..31)
    #pragma unroll
    for (int mf = 0; mf < 8; ++mf) {
        #pragma unroll
        for (int j = 0; j < 4; ++j) {
            const int rloc = wm * 128 + mf * 16 + lhi * 4 + j;
            const int row = rowBase + rloc;
            const int tg = tl[rloc];
            float mg[4];
            float M = -INFINITY, T = 0.f;
            #pragma unroll
            for (int nf = 0; nf < 4; ++nf) {
                float v = acc[mf][nf][j];
                float v2 = v * v;
                float mag2 = v2 + __shfl_xor(v2, 1);     // pair re/im
                int col = colBase + wn * 64 + nf * 16 + l15;
                bool valid = (col < 2 * NCOL);
                float m_ = valid ? sqrtf(mag2) : -INFINITY;
                mg[nf] = m_;
                M = fmaxf(M, m_);
                int q = col >> 1;
                if (valid && q == tg) T += sqrtf(mag2);
            }
            #pragma unroll
            for (int off = 1; off < 16; off <<= 1) M = fmaxf(M, __shfl_xor(M, off));
            float S = 0.f;
            #pragma unroll
            for (int nf = 0; nf < 4; ++nf) S += __expf(mg[nf] - M);
            #pragma unroll
            for (int off = 1; off < 16; off <<= 1) S += __shfl_xor(S, off);
            #pragma unroll
            for (int off = 1; off < 16; off <<= 1) T += __shfl_xor(T, off);
            if (l15 == 0) {
                part[((size_t)(aid * BROWS + row)) * 32 + chunk] =
                    make_float2(M, 0.5f * S);              // x0.5: re/im lane dup
                if ((tg >> 5) == chunk) tv[(size_t)aid * BROWS + row] = 0.5f * T;
            }
        }
    }
}

// ---------------- merge partials -> sum of nll ----------------
__global__ __launch_bounds__(256) void k2_reduce(const float2* __restrict__ part,
                                                 const float* __restrict__ tv,
                                                 float* __restrict__ acc)
{
    int r = blockIdx.x * 256 + threadIdx.x;   // 3*16384 rows
    const float2* p = part + (size_t)r * 32;
    float M = -INFINITY;
    #pragma unroll
    for (int i = 0; i < 32; ++i) M = fmaxf(M, p[i].x);
    float S = 0.f;
    #pragma unroll
    for (int i = 0; i < 32; ++i) { float2 c = p[i]; S += c.y * __expf(c.x - M); }
    float nll = M + __logf(S) - tv[r];
    #pragma unroll
    for (int off = 1; off < 64; off <<= 1) nll += __shfl_xor(nll, off);
    __shared__ float sp[4];
    if ((threadIdx.x & 63) == 0) sp[threadIdx.x >> 6] = nll;
    __syncthreads();
    if (threadIdx.x == 0) atomicAdd(acc + 1, sp[0] + sp[1] + sp[2] + sp[3]);
}

__global__ void final_kernel(const float* __restrict__ acc, float* __restrict__ out)
{
    if (threadIdx.x == 0)
        out[0] = acc[0] * (1.0f / (float)BROWS)
               + 0.5f * acc[1] * (1.0f / (3.0f * (float)BROWS));
}

extern "C" void kernel_launch(void* const* d_in, const int* in_sizes, int n_in,
                              void* d_out, int out_size, void* d_ws, size_t ws_size,
                              hipStream_t stream)
{
    const float* logits  = (const float*)d_in[0];
    const int*   targets = (const int*)d_in[1];
    float* out = (float*)d_out;

    float*          acc  = (float*)d_ws;
    unsigned short* Bg   = (unsigned short*)((char*)d_ws + 256);
    float2*         part = (float2*)((char*)d_ws + 256 + 12582912);
    float*          tv   = (float*)((char*)d_ws + 256 + 2 * 12582912);

    hipMemsetAsync(acc, 0, 2 * sizeof(float), stream);
    gen_b<<<12288, 256, 0, stream>>>(Bg);
    ce_kernel<<<BROWS, 256, 0, stream>>>(logits, targets, acc);
    frft2<<<dim3(512, 3), 512, 0, stream>>>(logits, targets, Bg, part, tv);
    k2_reduce<<<192, 256, 0, stream>>>(part, tv, acc);
    final_kernel<<<1, 64, 0, stream>>>(acc, out);
}

// Round 7
// 636.702 us; speedup vs baseline: 1.1825x; 1.1482x over previous
//
#include <hip/hip_runtime.h>

#define BROWS 16384
#define NCOL  1000
#define NPRIME 2048                       // interleaved re/im cols
#define BAELEM ((size_t)NPRIME * 1024)    // ushorts per alpha

typedef __attribute__((ext_vector_type(8))) short short8;
typedef __attribute__((ext_vector_type(4))) float f32x4;

__device__ inline unsigned short bf16_rn(float f) {
    unsigned int u = __float_as_uint(f);
    unsigned int r = (u + 0x7fffu + ((u >> 16) & 1u)) >> 16;
    return (unsigned short)r;
}

__device__ inline void gload16(const void* g, void* l) {
    __builtin_amdgcn_global_load_lds(
        (const __attribute__((address_space(1))) unsigned int*)g,
        (__attribute__((address_space(3))) unsigned int*)l, 16, 0, 0);
}

__device__ inline short8 pack8(float4 a, float4 b) {
    short8 r;
    r[0] = (short)bf16_rn(a.x); r[1] = (short)bf16_rn(a.y);
    r[2] = (short)bf16_rn(a.z); r[3] = (short)bf16_rn(a.w);
    r[4] = (short)bf16_rn(b.x); r[5] = (short)bf16_rn(b.y);
    r[6] = (short)bf16_rn(b.z); r[7] = (short)bf16_rn(b.w);
    return r;
}

// ---------------- B' generation: [alpha][kt16][col 2048][64k], swizzled 16B slots ----
// Per (q, slot-of-8-m): 8 sincos -> one 16B store to cos-col (2q) and sin-col (2q+1).
// Swizzle: in-row byte ^= (col&7)<<4  (rows are 128B), matching frft2's ds_read.
__global__ __launch_bounds__(256) void gen_b(unsigned short* __restrict__ Bg)
{
    unsigned int idx = blockIdx.x * 256u + threadIdx.x;   // 3 * 2^17
    int a = idx >> 17;
    unsigned int rem = idx & 131071u;
    int q = rem >> 7, s = rem & 127;
    short8 cs = {}, sn = {};
    if (q < NCOL && s < 125) {
        #pragma unroll
        for (int j = 0; j < 8; ++j) {
            int m = s * 8 + j;
            float cv, sv;
            if (a == 1) {
                int p = (q * m) % 1000;
                float ang = 6.28318530717958f * 0.001f * (float)p;
                __sincosf(ang, &sv, &cv);
                sv = -sv;
            } else {
                float coef = (a == 0) ? 3.14159265358979f * 0.5e-6f
                                      : 3.14159265358979f * 1.5e-6f;
                float V = 0.5f * (float)(m * m + q * q) - 2.0f * (float)(q * m);
                __sincosf(coef * V, &sv, &cv);
                cv *= 0.001f; sv *= 0.001f;
            }
            cs[j] = (short)bf16_rn(cv);
            sn[j] = (short)bf16_rn(sv);
        }
    }
    int kt = s >> 3;
    int bb = (s & 7) * 16;
    size_t base = (size_t)a * BAELEM + (size_t)kt * 131072;
    int c0 = 2 * q, c1 = 2 * q + 1;
    *(short8*)(Bg + base + c0 * 64 + (((bb) ^ ((c0 & 7) << 4)) >> 1)) = cs;
    *(short8*)(Bg + base + c1 * 64 + (((bb) ^ ((c1 & 7) << 4)) >> 1)) = sn;
}

// ---------------- plain CE: one wave per row, single pass in registers ----------------
__global__ __launch_bounds__(256) void ce_kernel(const float* __restrict__ logits,
                                                 const int* __restrict__ tgt,
                                                 float* __restrict__ acc)
{
    int w = threadIdx.x >> 6, l = threadIdx.x & 63;
    int row = blockIdx.x * 4 + w;
    const float* p = logits + (size_t)row * NCOL;
    float v[16];
    #pragma unroll
    for (int i = 0; i < 15; ++i) v[i] = p[l + i * 64];
    bool tail = (l < 40);
    v[15] = tail ? p[l + 960] : -INFINITY;
    float M = v[0];
    #pragma unroll
    for (int i = 1; i < 16; ++i) M = fmaxf(M, v[i]);
    #pragma unroll
    for (int off = 1; off < 64; off <<= 1) M = fmaxf(M, __shfl_xor(M, off));
    float S = 0.f;
    #pragma unroll
    for (int i = 0; i < 15; ++i) S += __expf(v[i] - M);
    if (tail) S += __expf(v[15] - M);
    #pragma unroll
    for (int off = 1; off < 64; off <<= 1) S += __shfl_xor(S, off);
    __shared__ float sp[4];
    if (l == 0) sp[w] = M + __logf(S) - p[tgt[row]];
    __syncthreads();
    if (threadIdx.x == 0) atomicAdd(acc, sp[0] + sp[1] + sp[2] + sp[3]);
}

// ---------------- 256x256 tile, BK=64, 4x16-MFMA phases, dbuf LDS (128KB) ----------
// grid (512,3): bx&63=row-block, bx>>6=col-block. 8 waves (2M x 4N), wave out 128x64.
// B staged via global_load_lds (pre-swizzled source); A reg-staged fp32->bf16 inline.
__global__ __launch_bounds__(512, 2) void frft2(const float* __restrict__ x,
                                                const int* __restrict__ tgt,
                                                const unsigned short* __restrict__ Bg,
                                                float2* __restrict__ part,
                                                float* __restrict__ tv)
{
    __shared__ unsigned short lA[2][16384];
    __shared__ unsigned short lB[2][16384];

    const int tid = threadIdx.x;
    const int w = tid >> 6, l = tid & 63, l15 = l & 15, lhi = (l >> 4) & 3;
    const int wm = w >> 2, wn = w & 3;
    const int aid = blockIdx.y;
    const int rowBase = (blockIdx.x & 63) << 8;
    const int colBase = (blockIdx.x >> 6) << 8;
    const unsigned short* Ba = Bg + (size_t)aid * BAELEM + (size_t)colBase * 64;

    // A staging: thread -> (row rl, 32-k half h); 4 swizzled 16B slots
    const int rl = tid >> 1, h = tid & 1;
    const float* xs = x + (size_t)(rowBase + rl) * NCOL + h * 32;
    int wb[4];
    #pragma unroll
    for (int j = 0; j < 4; ++j)
        wb[j] = rl * 128 + ((16 * (4 * h + j)) ^ ((rl & 7) << 4));

    // B gload: issue i -> segment (i*8+w): global +512 ushorts, LDS +1024B
    int gofs[4], lofs[4];
    #pragma unroll
    for (int i = 0; i < 4; ++i) {
        gofs[i] = (i * 8 + w) * 512 + l * 8;
        lofs[i] = (i * 8 + w) * 1024;
    }

    // fragment read byte-addrs (kk=0); kk=1 is ^64 (swizzle bits 4-6, no carry)
    int ar0[8], br0[4];
    #pragma unroll
    for (int mf = 0; mf < 8; ++mf) {
        int r = wm * 128 + mf * 16 + l15;
        ar0[mf] = r * 128 + ((lhi * 16) ^ ((r & 7) << 4));
    }
    #pragma unroll
    for (int nf = 0; nf < 4; ++nf) {
        int c = wn * 64 + nf * 16 + l15;
        br0[nf] = c * 128 + ((lhi * 16) ^ ((c & 7) << 4));
    }

    char* lAc = (char*)&lA[0][0];
    char* lBc = (char*)&lB[0][0];

    f32x4 acc[8][4] = {};

    // ---- prologue: stage tile 0 into buffer 0 ----
    {
        #pragma unroll
        for (int i = 0; i < 4; ++i) gload16(Ba + gofs[i], lBc + lofs[i]);
        float4 g0 = *(const float4*)(xs);      float4 g1 = *(const float4*)(xs + 4);
        float4 g2 = *(const float4*)(xs + 8);  float4 g3 = *(const float4*)(xs + 12);
        float4 g4 = *(const float4*)(xs + 16); float4 g5 = *(const float4*)(xs + 20);
        float4 g6 = *(const float4*)(xs + 24); float4 g7 = *(const float4*)(xs + 28);
        *(short8*)(lAc + wb[0]) = pack8(g0, g1);
        *(short8*)(lAc + wb[1]) = pack8(g2, g3);
        *(short8*)(lAc + wb[2]) = pack8(g4, g5);
        *(short8*)(lAc + wb[3]) = pack8(g6, g7);
    }
    __syncthreads();

#define MFMA16(MB)                                                                        \
    acc[MB+0][0] = __builtin_amdgcn_mfma_f32_16x16x32_bf16(a0, b0, acc[MB+0][0], 0, 0, 0); \
    acc[MB+0][1] = __builtin_amdgcn_mfma_f32_16x16x32_bf16(a0, b1, acc[MB+0][1], 0, 0, 0); \
    acc[MB+0][2] = __builtin_amdgcn_mfma_f32_16x16x32_bf16(a0, b2, acc[MB+0][2], 0, 0, 0); \
    acc[MB+0][3] = __builtin_amdgcn_mfma_f32_16x16x32_bf16(a0, b3, acc[MB+0][3], 0, 0, 0); \
    acc[MB+1][0] = __builtin_amdgcn_mfma_f32_16x16x32_bf16(a1, b0, acc[MB+1][0], 0, 0, 0); \
    acc[MB+1][1] = __builtin_amdgcn_mfma_f32_16x16x32_bf16(a1, b1, acc[MB+1][1], 0, 0, 0); \
    acc[MB+1][2] = __builtin_amdgcn_mfma_f32_16x16x32_bf16(a1, b2, acc[MB+1][2], 0, 0, 0); \
    acc[MB+1][3] = __builtin_amdgcn_mfma_f32_16x16x32_bf16(a1, b3, acc[MB+1][3], 0, 0, 0); \
    acc[MB+2][0] = __builtin_amdgcn_mfma_f32_16x16x32_bf16(a2, b0, acc[MB+2][0], 0, 0, 0); \
    acc[MB+2][1] = __builtin_amdgcn_mfma_f32_16x16x32_bf16(a2, b1, acc[MB+2][1], 0, 0, 0); \
    acc[MB+2][2] = __builtin_amdgcn_mfma_f32_16x16x32_bf16(a2, b2, acc[MB+2][2], 0, 0, 0); \
    acc[MB+2][3] = __builtin_amdgcn_mfma_f32_16x16x32_bf16(a2, b3, acc[MB+2][3], 0, 0, 0); \
    acc[MB+3][0] = __builtin_amdgcn_mfma_f32_16x16x32_bf16(a3, b0, acc[MB+3][0], 0, 0, 0); \
    acc[MB+3][1] = __builtin_amdgcn_mfma_f32_16x16x32_bf16(a3, b1, acc[MB+3][1], 0, 0, 0); \
    acc[MB+3][2] = __builtin_amdgcn_mfma_f32_16x16x32_bf16(a3, b2, acc[MB+3][2], 0, 0, 0); \
    acc[MB+3][3] = __builtin_amdgcn_mfma_f32_16x16x32_bf16(a3, b3, acc[MB+3][3], 0, 0, 0);

    #pragma unroll 2
    for (int kt = 0; kt < 16; ++kt) {
        const int curb = (kt & 1) << 15;
        const int nxtb = curb ^ 32768;
        const bool pre = (kt < 15);
        const int ktn = kt + 1;

        short8 a0, a1, a2, a3, b0, b1, b2, b3;
        float4 f0 = {0,0,0,0}, f1 = {0,0,0,0}, f2 = {0,0,0,0}, f3 = {0,0,0,0};
        float4 f4 = {0,0,0,0}, f5 = {0,0,0,0}, f6 = {0,0,0,0}, f7 = {0,0,0,0};

        // ---- P0: kk0, mf0-3; issue B gloads 0-1 + A loads 0-1 for kt+1
        if (pre) {
            const unsigned short* bt = Ba + (size_t)ktn * 131072;
            gload16(bt + gofs[0], lBc + nxtb + lofs[0]);
            gload16(bt + gofs[1], lBc + nxtb + lofs[1]);
            const int k0 = ktn * 64 + h * 32;
            const float* xn = xs + ktn * 64;
            if (k0 < NCOL)     { f0 = *(const float4*)(xn);     f1 = *(const float4*)(xn + 4);  }
            if (k0 + 8 < NCOL) { f2 = *(const float4*)(xn + 8); f3 = *(const float4*)(xn + 12); }
        }
        a0 = *(const short8*)(lAc + curb + ar0[0]);
        a1 = *(const short8*)(lAc + curb + ar0[1]);
        a2 = *(const short8*)(lAc + curb + ar0[2]);
        a3 = *(const short8*)(lAc + curb + ar0[3]);
        b0 = *(const short8*)(lBc + curb + br0[0]);
        b1 = *(const short8*)(lBc + curb + br0[1]);
        b2 = *(const short8*)(lBc + curb + br0[2]);
        b3 = *(const short8*)(lBc + curb + br0[3]);
        __builtin_amdgcn_s_setprio(1);
        MFMA16(0)
        __builtin_amdgcn_s_setprio(0);
        __builtin_amdgcn_s_barrier();

        // ---- P1: kk0, mf4-7 (B reused); issue B gloads 2-3 + A loads 2-3
        if (pre) {
            const unsigned short* bt = Ba + (size_t)ktn * 131072;
            gload16(bt + gofs[2], lBc + nxtb + lofs[2]);
            gload16(bt + gofs[3], lBc + nxtb + lofs[3]);
            const int k0 = ktn * 64 + h * 32;
            const float* xn = xs + ktn * 64;
            if (k0 + 16 < NCOL) { f4 = *(const float4*)(xn + 16); f5 = *(const float4*)(xn + 20); }
            if (k0 + 24 < NCOL) { f6 = *(const float4*)(xn + 24); f7 = *(const float4*)(xn + 28); }
        }
        a0 = *(const short8*)(lAc + curb + ar0[4]);
        a1 = *(const short8*)(lAc + curb + ar0[5]);
        a2 = *(const short8*)(lAc + curb + ar0[6]);
        a3 = *(const short8*)(lAc + curb + ar0[7]);
        __builtin_amdgcn_s_setprio(1);
        MFMA16(4)
        __builtin_amdgcn_s_setprio(0);
        __builtin_amdgcn_s_barrier();

        // ---- P2: kk1, mf0-3; A stage writes 0-1
        a0 = *(const short8*)(lAc + curb + (ar0[0] ^ 64));
        a1 = *(const short8*)(lAc + curb + (ar0[1] ^ 64));
        a2 = *(const short8*)(lAc + curb + (ar0[2] ^ 64));
        a3 = *(const short8*)(lAc + curb + (ar0[3] ^ 64));
        b0 = *(const short8*)(lBc + curb + (br0[0] ^ 64));
        b1 = *(const short8*)(lBc + curb + (br0[1] ^ 64));
        b2 = *(const short8*)(lBc + curb + (br0[2] ^ 64));
        b3 = *(const short8*)(lBc + curb + (br0[3] ^ 64));
        if (pre) {
            *(short8*)(lAc + nxtb + wb[0]) = pack8(f0, f1);
            *(short8*)(lAc + nxtb + wb[1]) = pack8(f2, f3);
        }
        __builtin_amdgcn_s_setprio(1);
        MFMA16(0)
        __builtin_amdgcn_s_setprio(0);
        __builtin_amdgcn_s_barrier();

        // ---- P3: kk1, mf4-7; A stage writes 2-3; iteration-end full drain
        a0 = *(const short8*)(lAc + curb + (ar0[4] ^ 64));
        a1 = *(const short8*)(lAc + curb + (ar0[5] ^ 64));
        a2 = *(const short8*)(lAc + curb + (ar0[6] ^ 64));
        a3 = *(const short8*)(lAc + curb + (ar0[7] ^ 64));
        if (pre) {
            *(short8*)(lAc + nxtb + wb[2]) = pack8(f4, f5);
            *(short8*)(lAc + nxtb + wb[3]) = pack8(f6, f7);
        }
        __builtin_amdgcn_s_setprio(1);
        MFMA16(4)
        __builtin_amdgcn_s_setprio(0);
        __syncthreads();   // drains vmcnt (B gloads issued ~4 phases ago) + lgkm
    }
#undef MFMA16

    // ---- epilogue: per-row partial logsumexp over this wave's 64 cols ----
    int* tl = (int*)lAc;
    if (tid < 256) tl[tid] = tgt[rowBase + tid];
    __syncthreads();

    const int chunk = (colBase >> 6) + wn;
    #pragma unroll
    for (int mf = 0; mf < 8; ++mf) {
        #pragma unroll
        for (int j = 0; j < 4; ++j) {
            const int rloc = wm * 128 + mf * 16 + lhi * 4 + j;
            const int row = rowBase + rloc;
            const int tg = tl[rloc];
            float mg[4];
            float M = -INFINITY, T = 0.f;
            #pragma unroll
            for (int nf = 0; nf < 4; ++nf) {
                float v = acc[mf][nf][j];
                float v2 = v * v;
                float mag2 = v2 + __shfl_xor(v2, 1);     // pair re/im cols
                int col = colBase + wn * 64 + nf * 16 + l15;
                bool valid = (col < 2 * NCOL);
                float m_ = valid ? sqrtf(mag2) : -INFINITY;
                mg[nf] = m_;
                M = fmaxf(M, m_);
                if (valid && (col >> 1) == tg) T += sqrtf(mag2);
            }
            #pragma unroll
            for (int off = 1; off < 16; off <<= 1) M = fmaxf(M, __shfl_xor(M, off));
            float S = 0.f;
            #pragma unroll
            for (int nf = 0; nf < 4; ++nf) S += __expf(mg[nf] - M);
            #pragma unroll
            for (int off = 1; off < 16; off <<= 1) S += __shfl_xor(S, off);
            #pragma unroll
            for (int off = 1; off < 16; off <<= 1) T += __shfl_xor(T, off);
            if (l15 == 0) {
                part[((size_t)(aid * BROWS + row)) * 32 + chunk] =
                    make_float2(M, 0.5f * S);             // x0.5: re/im lane dup
                if ((tg >> 5) == chunk) tv[(size_t)aid * BROWS + row] = 0.5f * T;
            }
        }
    }
}

// ---------------- merge partials -> sum of nll ----------------
__global__ __launch_bounds__(256) void k2_reduce(const float2* __restrict__ part,
                                                 const float* __restrict__ tv,
                                                 float* __restrict__ acc)
{
    int r = blockIdx.x * 256 + threadIdx.x;
    const float2* p = part + (size_t)r * 32;
    float M = -INFINITY;
    #pragma unroll
    for (int i = 0; i < 32; ++i) M = fmaxf(M, p[i].x);
    float S = 0.f;
    #pragma unroll
    for (int i = 0; i < 32; ++i) { float2 c = p[i]; S += c.y * __expf(c.x - M); }
    float nll = M + __logf(S) - tv[r];
    #pragma unroll
    for (int off = 1; off < 64; off <<= 1) nll += __shfl_xor(nll, off);
    __shared__ float sp[4];
    if ((threadIdx.x & 63) == 0) sp[threadIdx.x >> 6] = nll;
    __syncthreads();
    if (threadIdx.x == 0) atomicAdd(acc + 1, sp[0] + sp[1] + sp[2] + sp[3]);
}

__global__ void final_kernel(const float* __restrict__ acc, float* __restrict__ out)
{
    if (threadIdx.x == 0)
        out[0] = acc[0] * (1.0f / (float)BROWS)
               + 0.5f * acc[1] * (1.0f / (3.0f * (float)BROWS));
}

extern "C" void kernel_launch(void* const* d_in, const int* in_sizes, int n_in,
                              void* d_out, int out_size, void* d_ws, size_t ws_size,
                              hipStream_t stream)
{
    const float* logits  = (const float*)d_in[0];
    const int*   targets = (const int*)d_in[1];
    float* out = (float*)d_out;

    float*          acc  = (float*)d_ws;
    unsigned short* Bg   = (unsigned short*)((char*)d_ws + 256);
    float2*         part = (float2*)((char*)d_ws + 256 + 12582912);
    float*          tv   = (float*)((char*)d_ws + 256 + 2 * 12582912);

    hipMemsetAsync(acc, 0, 2 * sizeof(float), stream);
    gen_b<<<1536, 256, 0, stream>>>(Bg);
    ce_kernel<<<4096, 256, 0, stream>>>(logits, targets, acc);
    frft2<<<dim3(512, 3), 512, 0, stream>>>(logits, targets, Bg, part, tv);
    k2_reduce<<<192, 256, 0, stream>>>(part, tv, acc);
    final_kernel<<<1, 64, 0, stream>>>(acc, out);
}

// Round 10
// 434.241 us; speedup vs baseline: 1.7338x; 1.4662x over previous
//
#include <hip/hip_runtime.h>

#define BROWS 16384
#define NCOL  1000
#define BAELEM ((size_t)2048 * 1024)     // ushorts per alpha in Bg

typedef __attribute__((ext_vector_type(8))) short short8;
typedef __attribute__((ext_vector_type(4))) float f32x4;

__device__ inline unsigned short bf16_rn(float f) {
    unsigned int u = __float_as_uint(f);
    unsigned int r = (u + 0x7fffu + ((u >> 16) & 1u)) >> 16;
    return (unsigned short)r;
}

__device__ inline void gload16(const void* g, void* l) {
    __builtin_amdgcn_global_load_lds(
        (const __attribute__((address_space(1))) unsigned int*)g,
        (__attribute__((address_space(3))) unsigned int*)l, 16, 0, 0);
}

__device__ inline short8 pack8(float4 a, float4 b) {
    short8 r;
    r[0] = (short)bf16_rn(a.x); r[1] = (short)bf16_rn(a.y);
    r[2] = (short)bf16_rn(a.z); r[3] = (short)bf16_rn(a.w);
    r[4] = (short)bf16_rn(b.x); r[5] = (short)bf16_rn(b.y);
    r[6] = (short)bf16_rn(b.z); r[7] = (short)bf16_rn(b.w);
    return r;
}

// ---------------- B' generation: [alpha][kt16][col 2048][64k], swizzled 16B slots ----
// Swizzle: byte-within-128B-row ^= (col&7)<<4, matching frft3's ds_read addressing.
__global__ __launch_bounds__(256) void gen_b(unsigned short* __restrict__ Bg)
{
    unsigned int idx = blockIdx.x * 256u + threadIdx.x;   // 3 * 2^17
    int a = idx >> 17;
    unsigned int rem = idx & 131071u;
    int q = rem >> 7, s = rem & 127;
    short8 cs = {}, sn = {};
    if (q < NCOL && s < 125) {
        #pragma unroll
        for (int j = 0; j < 8; ++j) {
            int m = s * 8 + j;
            float cv, sv;
            if (a == 1) {
                int p = (q * m) % 1000;
                float ang = 6.28318530717958f * 0.001f * (float)p;
                __sincosf(ang, &sv, &cv);
                sv = -sv;
            } else {
                float coef = (a == 0) ? 3.14159265358979f * 0.5e-6f
                                      : 3.14159265358979f * 1.5e-6f;
                float V = 0.5f * (float)(m * m + q * q) - 2.0f * (float)(q * m);
                __sincosf(coef * V, &sv, &cv);
                cv *= 0.001f; sv *= 0.001f;
            }
            cs[j] = (short)bf16_rn(cv);
            sn[j] = (short)bf16_rn(sv);
        }
    }
    int kt = s >> 3;
    int bb = (s & 7) * 16;
    size_t base = (size_t)a * BAELEM + (size_t)kt * 131072;
    int c0 = 2 * q, c1 = 2 * q + 1;
    *(short8*)(Bg + base + c0 * 64 + (((bb) ^ ((c0 & 7) << 4)) >> 1)) = cs;
    *(short8*)(Bg + base + c1 * 64 + (((bb) ^ ((c1 & 7) << 4)) >> 1)) = sn;
}

// ---------------- x (fp32) -> Ap (bf16): [kt16][row 16384][64k], same swizzle --------
__global__ __launch_bounds__(256) void conv_a(const float* __restrict__ x,
                                              unsigned short* __restrict__ Ap)
{
    unsigned int u = blockIdx.x * 256u + threadIdx.x;     // 2^21
    int c16 = u & 7;
    int row = (u >> 3) & 16383;
    int kt  = u >> 17;
    int k0 = kt * 64 + c16 * 8;
    short8 pk = {};
    if (k0 + 8 <= NCOL) {
        const float* p = x + (size_t)row * NCOL + k0;
        float4 f0 = *(const float4*)p;
        float4 f1 = *(const float4*)(p + 4);
        pk = pack8(f0, f1);
    }
    size_t dst = (size_t)kt * (16384 * 64) + (size_t)row * 64
               + ((unsigned)((c16 * 16) ^ ((row & 7) << 4)) >> 1);
    *(short8*)(Ap + dst) = pk;
}

// ---------------- plain CE: one wave per row, single pass in registers ----------------
__global__ __launch_bounds__(256) void ce_kernel(const float* __restrict__ logits,
                                                 const int* __restrict__ tgt,
                                                 float* __restrict__ acc)
{
    int w = threadIdx.x >> 6, l = threadIdx.x & 63;
    int row = blockIdx.x * 4 + w;
    const float* p = logits + (size_t)row * NCOL;
    float v[16];
    #pragma unroll
    for (int i = 0; i < 15; ++i) v[i] = p[l + i * 64];
    bool tail = (l < 40);
    v[15] = tail ? p[l + 960] : -INFINITY;
    float M = v[0];
    #pragma unroll
    for (int i = 1; i < 16; ++i) M = fmaxf(M, v[i]);
    #pragma unroll
    for (int off = 1; off < 64; off <<= 1) M = fmaxf(M, __shfl_xor(M, off));
    float S = 0.f;
    #pragma unroll
    for (int i = 0; i < 15; ++i) S += __expf(v[i] - M);
    if (tail) S += __expf(v[15] - M);
    #pragma unroll
    for (int off = 1; off < 64; off <<= 1) S += __shfl_xor(S, off);
    __shared__ float sp[4];
    if (l == 0) sp[w] = M + __logf(S) - p[tgt[row]];
    __syncthreads();
    if (threadIdx.x == 0) atomicAdd(acc, sp[0] + sp[1] + sp[2] + sp[3]);
}

// ---------------- m97-style 128x128 tile GEMM + partial-logsumexp epilogue ----------
// grid (2048, 3): bx>>4 = row-block (128 rows), bx&15 = col-block (128 of 2048 cols).
// 4 waves (2M x 2N), wave tile 64x64; BK=64, single-buffered LDS (32 KB);
// both operands staged via global_load_lds from pre-swizzled bf16 buffers.
__global__ __launch_bounds__(256, 4) void frft3(const unsigned short* __restrict__ Ap,
                                                const unsigned short* __restrict__ Bg,
                                                const int* __restrict__ tgt,
                                                float2* __restrict__ part,
                                                float* __restrict__ tv)
{
    __shared__ unsigned short lA[8192];
    __shared__ unsigned short lB[8192];

    const int tid = threadIdx.x;
    const int w = tid >> 6, l = tid & 63, l15 = l & 15, lhi = l >> 4;
    const int wm = w >> 1, wn = w & 1;
    const int aid = blockIdx.y;
    const int rowBase = (blockIdx.x >> 4) << 7;
    const int colBase = (blockIdx.x & 15) << 7;

    const unsigned short* As = Ap + (size_t)rowBase * 64;
    const unsigned short* Bs = Bg + (size_t)aid * BAELEM + (size_t)colBase * 64;

    int gseg[4], lseg[4];
    #pragma unroll
    for (int i = 0; i < 4; ++i) {
        int s = i * 4 + w;               // 16 segments of 1KB per operand tile
        gseg[i] = s * 512 + l * 8;       // ushort units
        lseg[i] = s * 1024;              // bytes
    }

    int ar[4], br[4];
    #pragma unroll
    for (int mf = 0; mf < 4; ++mf) {
        int r = wm * 64 + mf * 16 + l15;
        ar[mf] = r * 128 + ((lhi * 16) ^ ((r & 7) << 4));
    }
    #pragma unroll
    for (int nf = 0; nf < 4; ++nf) {
        int c = wn * 64 + nf * 16 + l15;
        br[nf] = c * 128 + ((lhi * 16) ^ ((c & 7) << 4));
    }

    char* lAc = (char*)lA;
    char* lBc = (char*)lB;
    f32x4 acc[4][4] = {};

    for (int kt = 0; kt < 16; ++kt) {
        const unsigned short* at = As + (size_t)kt * (16384 * 64);
        const unsigned short* bt = Bs + (size_t)kt * 131072;
        #pragma unroll
        for (int i = 0; i < 4; ++i) {
            gload16(at + gseg[i], lAc + lseg[i]);
            gload16(bt + gseg[i], lBc + lseg[i]);
        }
        __syncthreads();                 // drains vmcnt: tile resident
        #pragma unroll
        for (int kk = 0; kk < 2; ++kk) {
            const int kx = kk << 6;      // bit 6 flip = second 32-k half
            short8 af[4], bf[4];
            #pragma unroll
            for (int i = 0; i < 4; ++i) {
                af[i] = *(const short8*)(lAc + (ar[i] ^ kx));
                bf[i] = *(const short8*)(lBc + (br[i] ^ kx));
            }
            #pragma unroll
            for (int mf = 0; mf < 4; ++mf)
                #pragma unroll
                for (int nf = 0; nf < 4; ++nf)
                    acc[mf][nf] = __builtin_amdgcn_mfma_f32_16x16x32_bf16(
                        af[mf], bf[nf], acc[mf][nf], 0, 0, 0);
        }
        __syncthreads();                 // all reads done before next stage
    }

    // ---- epilogue: per-row partial logsumexp over this wave's 64 cols ----
    int* tl = (int*)lAc;
    if (tid < 128) tl[tid] = tgt[rowBase + tid];
    __syncthreads();

    const int chunk = (colBase >> 6) + wn;     // 0..31
    #pragma unroll
    for (int mf = 0; mf < 4; ++mf) {
        #pragma unroll
        for (int j = 0; j < 4; ++j) {
            const int rloc = wm * 64 + mf * 16 + lhi * 4 + j;
            const int row = rowBase + rloc;
            const int tg = tl[rloc];
            float mg[4];
            float M = -INFINITY, T = 0.f;
            #pragma unroll
            for (int nf = 0; nf < 4; ++nf) {
                float v = acc[mf][nf][j];
                float v2 = v * v;
                float mag2 = v2 + __shfl_xor(v2, 1);   // pair re/im cols
                int col = colBase + wn * 64 + nf * 16 + l15;
                bool valid = (col < 2 * NCOL);
                float m_ = valid ? sqrtf(mag2) : -INFINITY;
                mg[nf] = m_;
                M = fmaxf(M, m_);
                if (valid && (col >> 1) == tg) T += sqrtf(mag2);
            }
            #pragma unroll
            for (int off = 1; off < 16; off <<= 1) M = fmaxf(M, __shfl_xor(M, off));
            float S = 0.f;
            #pragma unroll
            for (int nf = 0; nf < 4; ++nf) S += __expf(mg[nf] - M);
            #pragma unroll
            for (int off = 1; off < 16; off <<= 1) S += __shfl_xor(S, off);
            #pragma unroll
            for (int off = 1; off < 16; off <<= 1) T += __shfl_xor(T, off);
            if (l15 == 0) {
                part[((size_t)(aid * BROWS + row)) * 32 + chunk] =
                    make_float2(M, 0.5f * S);          // x0.5: re/im lane dup
                if ((tg >> 5) == chunk) tv[(size_t)aid * BROWS + row] = 0.5f * T;
            }
        }
    }
}

// ---------------- merge partials -> sum of nll ----------------
__global__ __launch_bounds__(256) void k2_reduce(const float2* __restrict__ part,
                                                 const float* __restrict__ tv,
                                                 float* __restrict__ acc)
{
    int r = blockIdx.x * 256 + threadIdx.x;
    const float2* p = part + (size_t)r * 32;
    float M = -INFINITY;
    #pragma unroll
    for (int i = 0; i < 32; ++i) M = fmaxf(M, p[i].x);
    float S = 0.f;
    #pragma unroll
    for (int i = 0; i < 32; ++i) { float2 c = p[i]; S += c.y * __expf(c.x - M); }
    float nll = M + __logf(S) - tv[r];
    #pragma unroll
    for (int off = 1; off < 64; off <<= 1) nll += __shfl_xor(nll, off);
    __shared__ float sp[4];
    if ((threadIdx.x & 63) == 0) sp[threadIdx.x >> 6] = nll;
    __syncthreads();
    if (threadIdx.x == 0) atomicAdd(acc + 1, sp[0] + sp[1] + sp[2] + sp[3]);
}

__global__ void final_kernel(const float* __restrict__ acc, float* __restrict__ out)
{
    if (threadIdx.x == 0)
        out[0] = acc[0] * (1.0f / (float)BROWS)
               + 0.5f * acc[1] * (1.0f / (3.0f * (float)BROWS));
}

extern "C" void kernel_launch(void* const* d_in, const int* in_sizes, int n_in,
                              void* d_out, int out_size, void* d_ws, size_t ws_size,
                              hipStream_t stream)
{
    const float* logits  = (const float*)d_in[0];
    const int*   targets = (const int*)d_in[1];
    float* out = (float*)d_out;

    float*          acc  = (float*)d_ws;
    unsigned short* Bg   = (unsigned short*)((char*)d_ws + 256);
    float2*         part = (float2*)((char*)d_ws + 256 + 12582912);
    float*          tv   = (float*)((char*)d_ws + 256 + 2 * 12582912);
    unsigned short* Ap   = (unsigned short*)((char*)d_ws + 256 + 2 * 12582912 + 196608);

    hipMemsetAsync(acc, 0, 2 * sizeof(float), stream);
    gen_b<<<1536, 256, 0, stream>>>(Bg);
    conv_a<<<8192, 256, 0, stream>>>(logits, Ap);
    ce_kernel<<<4096, 256, 0, stream>>>(logits, targets, acc);
    frft3<<<dim3(2048, 3), 256, 0, stream>>>(Ap, Bg, targets, part, tv);
    k2_reduce<<<192, 256, 0, stream>>>(part, tv, acc);
    final_kernel<<<1, 64, 0, stream>>>(acc, out);
}